// Round 6
// baseline (201.779 us; speedup 1.0000x reference)
//
#include <hip/hip_runtime.h>

typedef _Float16 half8 __attribute__((ext_vector_type(8)));
typedef _Float16 half4 __attribute__((ext_vector_type(4)));
typedef _Float16 half2 __attribute__((ext_vector_type(2)));
typedef float f32x4 __attribute__((ext_vector_type(4)));
typedef unsigned int u32x4 __attribute__((ext_vector_type(4)));

#define MFMA16(a, b, c) __builtin_amdgcn_mfma_f32_16x16x32_f16((a), (b), (c), 0, 0, 0)
#define EXP2F(x) __builtin_amdgcn_exp2f(x)

#define GLOBAL_LOAD_LDS16(gptr, lptr)                                        \
    __builtin_amdgcn_global_load_lds(                                        \
        (const __attribute__((address_space(1))) void*)(gptr),               \
        (__attribute__((address_space(3))) void*)(lptr), 16, 0, 0)

// Q is pre-scaled by softmax_scale * log2(e) in the qkv epilogue.
#define QSCALE 0.18033688f  // 0.125 * log2(e)

#define SCHED0() __builtin_amdgcn_sched_barrier(0)
#define BARRIER() do { SCHED0(); asm volatile("" ::: "memory");            \
                       __builtin_amdgcn_s_barrier();                        \
                       asm volatile("" ::: "memory"); SCHED0(); } while (0)
#define WAITV(N) asm volatile("s_waitcnt vmcnt(" #N ")" ::: "memory")
#define WAITLG(N) asm volatile("s_waitcnt lgkmcnt(" #N ")" ::: "memory")

// ---------------- fused prep: cast x + transpose-cast both weights ----------------

__global__ __launch_bounds__(256) void prep_kernel(const float* __restrict__ x,
                                                   const float* __restrict__ Wqkv,
                                                   const float* __restrict__ Wproj,
                                                   _Float16* __restrict__ Xh,
                                                   _Float16* __restrict__ Wqt,
                                                   _Float16* __restrict__ Wpt) {
    const int bid = blockIdx.x;
    const int tid = threadIdx.x;
    if (bid < 4096) {
        int i = bid * 1024 + tid * 4;
        float4 v = *(const float4*)(x + i);
        half4 h = {(_Float16)v.x, (_Float16)v.y, (_Float16)v.z, (_Float16)v.w};
        *(half4*)(Xh + i) = h;
        return;
    }
    __shared__ _Float16 tile[32][33];
    const float* W;
    _Float16* Wt;
    int n0, k0, N;
    if (bid < 7168) {
        int t = bid - 4096;
        W = Wqkv; Wt = Wqt; N = 3072;
        n0 = (t % 96) * 32; k0 = (t / 96) * 32;
    } else {
        int t = bid - 7168;
        W = Wproj; Wt = Wpt; N = 1024;
        n0 = (t & 31) * 32; k0 = (t >> 5) * 32;
    }
    int c = tid & 31, r4 = tid >> 5;
    for (int i = 0; i < 4; i++) {
        int r = r4 + i * 8;
        tile[r][c] = (_Float16)W[(k0 + r) * N + n0 + c];
    }
    __syncthreads();
    for (int i = 0; i < 4; i++) {
        int r = r4 + i * 8;  // n within tile
        Wt[(n0 + r) * 1024 + k0 + c] = tile[c][r];
    }
}

// ---------------- QKV GEMM: 256x256-tile 8-phase counted-vmcnt (T2+T3+T4+T5) ----------------

#define LOFF(ROW, Q) ((((ROW) >> 1) * 64) + \
    ((((((ROW) & 1) << 2) | (Q)) ^ (((ROW) >> 1) & 7)) * 8))

__global__ __launch_bounds__(512) void gemm_qkv(const _Float16* __restrict__ A,
                                                const _Float16* __restrict__ Bt,
                                                const float* __restrict__ bias,
                                                _Float16* __restrict__ Qo,
                                                _Float16* __restrict__ Ko,
                                                _Float16* __restrict__ Vto) {
    __shared__ _Float16 L[65536];  // [buf2][op2][kk2][8192 halfs] = 128 KB
    const int tid = threadIdx.x;
    const int lin = blockIdx.x;
    const int xcd = lin & 7, slot = lin >> 3;      // slot 0..23
    const int m0 = (xcd * 2 + slot / 12) * 256;    // 16 m-tiles
    const int n0 = (slot % 12) * 256;              // 12 n-tiles
    const int wave = tid >> 6, lane = tid & 63;
    const int wm = wave >> 2, wn = wave & 3;       // 2M x 4N waves
    const int quad = lane >> 4, l15 = lane & 15;

    // staging: linear GLL dest (lane*16B), pre-swizzled global source
    const int s8 = (tid & 7) ^ ((tid >> 3) & 7);   // logical 16B-slot (0..7)
    const int srow = (tid >> 3) * 2 + (s8 >> 2);   // logical row (round 0)
    const int scol = (s8 & 3) * 8;                 // logical col within kk-half
    const _Float16* Asrc = A + (size_t)(m0 + srow) * 1024 + scol;
    const _Float16* Bsrc = Bt + (size_t)(n0 + srow) * 1024 + scol;
    _Float16* Ldst = L + tid * 8;

#define STG(OP, KK, KT) do {                                                  \
    const _Float16* _g = ((OP) ? Bsrc : Asrc) + ((KT) & 15) * 64 + (KK) * 32; \
    _Float16* _l = Ldst + ((KT) & 1) * 32768 + (OP) * 16384 + (KK) * 8192;    \
    GLOBAL_LOAD_LDS16(_g, _l);                                                \
    GLOBAL_LOAD_LDS16(_g + 128 * 1024, _l + 4096);                            \
} while (0)

    const int arow = wm * 128 + l15;   // + MH*64 + fi*16
    const int brow = wn * 64 + l15;    // + nf*16

    f32x4 acc[8][4] = {};
    half8 af[4], bf[4];

#define PHASE(BUF, KK, MH, RDB, SOP, SKK, SKT, W4) do {                        \
    const _Float16* _ab = L + (BUF) * 32768 + (KK) * 8192;                     \
    const _Float16* _bb = _ab + 16384;                                         \
    if (RDB) {                                                                 \
        _Pragma("unroll") for (int nf = 0; nf < 4; nf++)                       \
            bf[nf] = *(const half8*)(_bb + LOFF(brow + nf * 16, quad));        \
    }                                                                          \
    _Pragma("unroll") for (int fi = 0; fi < 4; fi++)                           \
        af[fi] = *(const half8*)(_ab + LOFF(arow + (MH) * 64 + fi * 16, quad));\
    STG(SOP, SKK, SKT);                                                        \
    BARRIER();                                                                 \
    __builtin_amdgcn_s_setprio(1);                                             \
    _Pragma("unroll") for (int fi = 0; fi < 4; fi++)                           \
        _Pragma("unroll") for (int nf = 0; nf < 4; nf++)                       \
            acc[(MH) * 4 + fi][nf] = MFMA16(af[fi], bf[nf],                    \
                                            acc[(MH) * 4 + fi][nf]);           \
    __builtin_amdgcn_s_setprio(0);                                             \
    if (W4) { WAITV(4); }                                                      \
    BARRIER();                                                                 \
} while (0)

    // prologue: tile0 complete + tile1 lo-halves in flight
    STG(0, 0, 0); STG(1, 0, 0); STG(0, 1, 0); STG(1, 1, 0);
    STG(0, 0, 1); STG(1, 0, 1);
    WAITV(4);           // tile0's 8 loads done; tile1 lo (4 loads) in flight
    BARRIER();

    for (int i = 0; i < 8; ++i) {
        const int ta = 2 * i, tb = 2 * i + 1;
        PHASE(0, 0, 0, 1, 0, 1, tb,     0);  // p1: +stage A-hi(t+1)
        PHASE(0, 0, 1, 0, 1, 1, tb,     0);  // p2: +stage B-hi(t+1)
        PHASE(0, 1, 0, 1, 0, 0, ta + 2, 0);  // p3: +stage A-lo(t+2)
        PHASE(0, 1, 1, 0, 1, 0, ta + 2, 1);  // p4: +stage B-lo(t+2); vmcnt(4)
        PHASE(1, 0, 0, 1, 0, 1, ta + 2, 0);  // p5: +stage A-hi(t+2)
        PHASE(1, 0, 1, 0, 1, 1, ta + 2, 0);  // p6: +stage B-hi(t+2)
        PHASE(1, 1, 0, 1, 0, 0, tb + 2, 0);  // p7: +stage A-lo(t+3)
        PHASE(1, 1, 1, 0, 1, 0, tb + 2, 1);  // p8: +stage B-lo(t+3); vmcnt(4)
    }
    WAITV(0);  // drain trailing (wrapped) stages before epilogue / endpgm

    // epilogue: scatter to Q (scaled) / K / Vt. which is block-uniform.
    // V columns are stored SIGMA-PERMUTED within each 32-t block:
    //   t = 16h + 4q + r  ->  p = (t & ~31) | (q<<3) | (h<<2) | r
    // so attn's PV B-operand (native P pack) and V agree on k with a plain
    // contiguous LDS copy (no swizzled LDS stores -> no bank conflicts).
    const int which = n0 >> 10;
    const int hh = ((n0 + wn * 64) & 1023) >> 6;  // head idx (wave-uniform)
    float bv[4];
    const int gnb = n0 + wn * 64;
#pragma unroll
    for (int nf = 0; nf < 4; nf++) bv[nf] = bias[gnb + nf * 16 + l15];

#pragma unroll
    for (int mf = 0; mf < 8; mf++) {
        const int gm0 = m0 + wm * 128 + mf * 16 + quad * 4;
        const int b = gm0 >> 11, t0 = gm0 & 2047;
        const int bh = b * 16 + hh;
#pragma unroll
        for (int nf = 0; nf < 4; nf++) {
            const int dh = nf * 16 + l15;
            if (which == 2) {
                half4 hv;
#pragma unroll
                for (int r = 0; r < 4; r++)
                    hv[r] = (_Float16)(acc[mf][nf][r] + bv[nf]);
                const int p0 = (t0 & ~31) | (((t0 >> 2) & 3) << 3) | (((t0 >> 4) & 1) << 2);
                *(half4*)(&Vto[(size_t)(bh * 64 + dh) * 2048 + p0]) = hv;
            } else if (which == 0) {
#pragma unroll
                for (int r = 0; r < 4; r++)
                    Qo[((size_t)bh * 2048 + t0 + r) * 64 + dh] =
                        (_Float16)((acc[mf][nf][r] + bv[nf]) * QSCALE);
            } else {
#pragma unroll
                for (int r = 0; r < 4; r++)
                    Ko[((size_t)bh * 2048 + t0 + r) * 64 + dh] =
                        (_Float16)(acc[mf][nf][r] + bv[nf]);
            }
        }
    }
#undef PHASE
#undef STG
}

// ---------------- flash attention: ni-split, all-K32, K direct-from-global ----------------
// R6: (1) K fragments load straight from global (L2/L1-resident; 4 pw-waves
// share lines via L1) -> K LDS reads+writes GONE, LDS pipe load halved.
// Rolling prefetch: KB(t) issues before ni2=0 compute, KA(t+1) before ni2=1.
// (2) lacc ones-MFMA replaced by VALU adds on exp values + 2 shfl_xor at end
// (matrix -11%). (3) V stays LDS-dbuf (sigma in global layout), 1 barrier/tile.
// LDS 34 KB; VGPR capped 128 via launch_bounds(512,4).

static __device__ inline unsigned pk2(float a, float b) {
    half2 p;
    p.x = (_Float16)a;
    p.y = (_Float16)b;
    return __builtin_bit_cast(unsigned, p);
}

__global__ __launch_bounds__(512, 4) void attn_kernel(const _Float16* __restrict__ Qg,
                                                      const _Float16* __restrict__ Kg,
                                                      const _Float16* __restrict__ Vtg,
                                                      _Float16* __restrict__ AO) {
    __shared__ __align__(16) _Float16 Vs[2][64][136];    // 34 KB

    const int tid = threadIdx.x;
    const int bh = blockIdx.x;
    const int q0 = blockIdx.y * 128;
    const int b = bh >> 4, h = bh & 15;
    const int wave = tid >> 6, lane = tid & 63;
    const int pw = wave & 3;     // q-group (32 q)
    const int kh = wave >> 2;    // ni half: k-cols [kh*64, kh*64+64)
    const int quad = lane >> 4, l15 = lane & 15;

    half8 qf[2][2];
#pragma unroll
    for (int g = 0; g < 2; g++) {
        const int qrow = q0 + pw * 32 + g * 16 + l15;
#pragma unroll
        for (int kk = 0; kk < 2; kk++)
            qf[g][kk] = *(const half8*)(&Qg[(bh * 2048 + qrow) * 64 + kk * 32 + quad * 8]);
    }

    const _Float16* Kbase = Kg + (size_t)bh * 2048 * 64;
    const _Float16* Vbase = Vtg + (size_t)bh * 64 * 2048;

    // K per-lane base: row = kh*64 + (ni2*32 + j*16) + l15, col = quad*8 (+32)
    const _Float16* Kl = Kbase + (size_t)(kh * 64 + l15) * 64 + quad * 8;

    // V staging: plain contiguous copy (global already sigma-permuted)
    const int vrow = tid >> 4;           // 0..31 (+32 for second row)
    const int vgcol = (tid & 15) * 8;
    const _Float16* Vsrc = Vbase + (size_t)vrow * 2048 + vgcol;

    f32x4 oacc[2][4] = {};
    float lsum[2] = {0.f, 0.f};
    half8 vr0, vr1;
    half8 kAaa, kAab, kAba, kAbb, kBaa, kBab, kBba, kBbb;

// One ni2 sub-step: QK^T (4 K-frag regs) -> exp2 -> lsum adds -> pack -> PV.
#define ATTN_STEP(Kaa, Kab, Kba, Kbb, NI2, Vc) do {                            \
    f32x4 sA0 = {}, sB0 = {}, sA1 = {}, sB1 = {};                              \
    sA0 = MFMA16(Kaa, qf[0][0], sA0);                                          \
    sA0 = MFMA16(Kab, qf[0][1], sA0);                                          \
    sB0 = MFMA16(Kba, qf[0][0], sB0);                                          \
    sB0 = MFMA16(Kbb, qf[0][1], sB0);                                          \
    sA1 = MFMA16(Kaa, qf[1][0], sA1);                                          \
    sA1 = MFMA16(Kab, qf[1][1], sA1);                                          \
    sB1 = MFMA16(Kba, qf[1][0], sB1);                                          \
    sB1 = MFMA16(Kbb, qf[1][1], sB1);                                          \
    float a0 = EXP2F(sA0[0]), a1 = EXP2F(sA0[1]);                              \
    float a2 = EXP2F(sA0[2]), a3 = EXP2F(sA0[3]);                              \
    float b0 = EXP2F(sB0[0]), b1 = EXP2F(sB0[1]);                              \
    float b2 = EXP2F(sB0[2]), b3 = EXP2F(sB0[3]);                              \
    lsum[0] += ((a0 + a1) + (a2 + a3)) + ((b0 + b1) + (b2 + b3));              \
    u32x4 w0 = {pk2(a0, a1), pk2(a2, a3), pk2(b0, b1), pk2(b2, b3)};           \
    half8 bP0 = __builtin_bit_cast(half8, w0);                                 \
    float c0 = EXP2F(sA1[0]), c1 = EXP2F(sA1[1]);                              \
    float c2 = EXP2F(sA1[2]), c3 = EXP2F(sA1[3]);                              \
    float d0 = EXP2F(sB1[0]), d1 = EXP2F(sB1[1]);                              \
    float d2 = EXP2F(sB1[2]), d3 = EXP2F(sB1[3]);                              \
    lsum[1] += ((c0 + c1) + (c2 + c3)) + ((d0 + d1) + (d2 + d3));              \
    u32x4 w1 = {pk2(c0, c1), pk2(c2, c3), pk2(d0, d1), pk2(d2, d3)};           \
    half8 bP1 = __builtin_bit_cast(half8, w1);                                 \
    const int vcb = kh * 64 + (NI2) * 32 + quad * 8;                           \
    _Pragma("unroll") for (int di = 0; di < 4; di++) {                         \
        half8 av = *(const half8*)(&Vc[di * 16 + l15][vcb]);                   \
        oacc[0][di] = MFMA16(av, bP0, oacc[0][di]);                            \
        oacc[1][di] = MFMA16(av, bP1, oacc[1][di]);                            \
    }                                                                          \
} while (0)

    // prologue: V tile0 -> LDS; K tile0 ni2=0 frags in flight
    vr0 = *(const half8*)(Vsrc);
    vr1 = *(const half8*)(Vsrc + 32 * 2048);
    kAaa = *(const half8*)(Kl);
    kAab = *(const half8*)(Kl + 32);
    kAba = *(const half8*)(Kl + 1024);
    kAbb = *(const half8*)(Kl + 1056);
    *(half8*)(&Vs[0][vrow][vgcol]) = vr0;
    *(half8*)(&Vs[0][vrow + 32][vgcol]) = vr1;
    WAITLG(0);
    BARRIER();

    for (int kt = 0; kt < 16; kt++) {
        const int cur = kt & 1;
        const _Float16 (*Vc)[136] = Vs[cur];
        const int kbn = ((kt + 1) & 15) * 128;             // next V t-offset
        const size_t kon = (size_t)((kt + 1) & 15) * 8192; // next K tile
        const size_t koc = (size_t)kt * 8192;              // current K tile

        // issue next-tile V and current-tile ni2=1 K frags
        vr0 = *(const half8*)(Vsrc + kbn);
        vr1 = *(const half8*)(Vsrc + 32 * 2048 + kbn);
        kBaa = *(const half8*)(Kl + koc + 2048);
        kBab = *(const half8*)(Kl + koc + 2048 + 32);
        kBba = *(const half8*)(Kl + koc + 2048 + 1024);
        kBbb = *(const half8*)(Kl + koc + 2048 + 1056);

        ATTN_STEP(kAaa, kAab, kAba, kAbb, 0, Vc);

        // issue next-tile ni2=0 K frags (wrapped at kt=15; values unused)
        kAaa = *(const half8*)(Kl + kon);
        kAab = *(const half8*)(Kl + kon + 32);
        kAba = *(const half8*)(Kl + kon + 1024);
        kAbb = *(const half8*)(Kl + kon + 1056);

        ATTN_STEP(kBaa, kBab, kBba, kBbb, 1, Vc);

        // land next-tile V into the other buffer
        *(half8*)(&Vs[cur ^ 1][vrow][vgcol]) = vr0;
        *(half8*)(&Vs[cur ^ 1][vrow + 32][vgcol]) = vr1;
        WAITLG(0);
        BARRIER();
    }
#undef ATTN_STEP

    // quad-reduce lsum (each lane held its quad's 8-k partial per ni2)
    lsum[0] += __shfl_xor(lsum[0], 16, 64);
    lsum[0] += __shfl_xor(lsum[0], 32, 64);
    lsum[1] += __shfl_xor(lsum[1], 16, 64);
    lsum[1] += __shfl_xor(lsum[1], 32, 64);

    // ---- cross-wave (ni-half) combine: partials are pure sums ----
    float* cb = (float*)&Vs[0][0][0];   // 4096 floats (16 KB, fits buf 0)
    float* lb = (float*)&Vs[1][0][0];   // 512 floats used
    const int pid = pw * 64 + lane;  // 0..255, lane-major -> conflict-free

    __syncthreads();                 // all reads of Vs done before reuse
    if (kh == 1) {
#pragma unroll
        for (int g = 0; g < 2; g++)
#pragma unroll
            for (int di = 0; di < 2; di++)
#pragma unroll
                for (int j = 0; j < 4; j++)
                    cb[(((g << 1) | di) * 4 + j) * 256 + pid] = oacc[g][di][j];
        lb[pid * 2 + 0] = lsum[0];
        lb[pid * 2 + 1] = lsum[1];
    }
    __syncthreads();
    if (kh == 0) {
#pragma unroll
        for (int g = 0; g < 2; g++)
#pragma unroll
            for (int di = 0; di < 2; di++)
#pragma unroll
                for (int j = 0; j < 4; j++)
                    oacc[g][di][j] += cb[(((g << 1) | di) * 4 + j) * 256 + pid];
        lsum[0] += lb[pid * 2 + 0];
        lsum[1] += lb[pid * 2 + 1];
    }
    __syncthreads();
    if (kh == 1) {
#pragma unroll
        for (int g = 0; g < 2; g++)
#pragma unroll
            for (int di = 2; di < 4; di++)
#pragma unroll
                for (int j = 0; j < 4; j++)
                    cb[(((g << 1) | (di - 2)) * 4 + j) * 256 + pid] = oacc[g][di][j];
    }
    __syncthreads();
    if (kh == 0) {
#pragma unroll
        for (int g = 0; g < 2; g++)
#pragma unroll
            for (int di = 2; di < 4; di++)
#pragma unroll
                for (int j = 0; j < 4; j++)
                    oacc[g][di][j] += cb[(((g << 1) | (di - 2)) * 4 + j) * 256 + pid];

        for (int g = 0; g < 2; g++) {
            float inv = 1.f / lsum[g];
            const int qrow = q0 + pw * 32 + g * 16 + l15;
            for (int di = 0; di < 4; di++) {
                half4 hv;
                hv[0] = (_Float16)(oacc[g][di][0] * inv);
                hv[1] = (_Float16)(oacc[g][di][1] * inv);
                hv[2] = (_Float16)(oacc[g][di][2] * inv);
                hv[3] = (_Float16)(oacc[g][di][3] * inv);
                *(half4*)(&AO[(size_t)(b * 2048 + qrow) * 1024 + h * 64 + di * 16 + quad * 4]) = hv;
            }
        }
    }
}

// ---------------- proj GEMM: out[4096,1024] = AO @ Wp + bp (fp32 out) ----------------

__global__ __launch_bounds__(256) void gemm_proj(const _Float16* __restrict__ A,
                                                 const _Float16* __restrict__ Bt,
                                                 const float* __restrict__ bias,
                                                 float* __restrict__ out) {
    __shared__ _Float16 As[64][64];    //  8 KB
    __shared__ _Float16 Bs[128][64];   // 16 KB
    const int tid = threadIdx.x;
    const int lin = blockIdx.x + 8 * blockIdx.y;
    const int xcd = lin & 7, slot = lin >> 3;     // slot 0..63
    const int n0 = (slot >> 3) * 128;
    const int m0 = (xcd * 8 + (slot & 7)) * 64;
    const int wave = tid >> 6, lane = tid & 63;
    const int quad = lane >> 4, l15 = lane & 15;
    const int sw = l15 & 7;
    const int ldrowA = wave * 16 + (lane >> 3);
    const int ldrowB = wave * 32 + (lane >> 3);
    const int ldslot = (lane & 7) * 8;
    const int gcolA = (((lane & 7) ^ (ldrowA & 7))) * 8;
    const int gcolB = (((lane & 7) ^ (ldrowB & 7))) * 8;

    f32x4 acc[4][2] = {};
    for (int k0 = 0; k0 < 1024; k0 += 64) {
        __syncthreads();
        for (int i = 0; i < 2; i++) {
            int r = ldrowA + i * 8;
            GLOBAL_LOAD_LDS16(&A[(size_t)(m0 + r) * 1024 + k0 + gcolA], &As[r][ldslot]);
        }
        for (int i = 0; i < 4; i++) {
            int r = ldrowB + i * 8;
            GLOBAL_LOAD_LDS16(&Bt[(size_t)(n0 + r) * 1024 + k0 + gcolB], &Bs[r][ldslot]);
        }
        __syncthreads();
        for (int kk = 0; kk < 64; kk += 32) {
            const int rcol = (((kk >> 3) + quad) ^ sw) * 8;
            half8 af[4], bf[2];
            for (int mi = 0; mi < 4; mi++)
                af[mi] = *(const half8*)(&As[mi * 16 + l15][rcol]);
            for (int ni = 0; ni < 2; ni++)
                bf[ni] = *(const half8*)(&Bs[wave * 32 + ni * 16 + l15][rcol]);
            for (int mi = 0; mi < 4; mi++)
                for (int ni = 0; ni < 2; ni++)
                    acc[mi][ni] = MFMA16(af[mi], bf[ni], acc[mi][ni]);
        }
    }
    for (int mi = 0; mi < 4; mi++)
        for (int ni = 0; ni < 2; ni++) {
            int gn = n0 + wave * 32 + ni * 16 + l15;
            float bv = bias[gn];
            for (int r = 0; r < 4; r++) {
                int gm = m0 + mi * 16 + quad * 4 + r;
                out[(size_t)gm * 1024 + gn] = acc[mi][ni][r] + bv;
            }
        }
}

// ---------------- launch ----------------

extern "C" void kernel_launch(void* const* d_in, const int* in_sizes, int n_in,
                              void* d_out, int out_size, void* d_ws, size_t ws_size,
                              hipStream_t stream) {
    const float* x     = (const float*)d_in[0];
    const float* Wqkv  = (const float*)d_in[1];
    const float* bqkv  = (const float*)d_in[2];
    const float* Wproj = (const float*)d_in[3];
    const float* bproj = (const float*)d_in[4];
    float* out = (float*)d_out;

    char* ws = (char*)d_ws;
    const size_t MB = 1024 * 1024;
    _Float16* Xh  = (_Float16*)(ws + 0 * MB);   // [4096][1024]   8 MB
    _Float16* Wqt = (_Float16*)(ws + 8 * MB);   // [3072][1024]   6 MB
    _Float16* Wpt = (_Float16*)(ws + 14 * MB);  // [1024][1024]   2 MB
    _Float16* Qg  = (_Float16*)(ws + 16 * MB);  // [32][2048][64] 8 MB (pre-scaled)
    _Float16* Kg  = (_Float16*)(ws + 24 * MB);  // [32][2048][64] 8 MB
    _Float16* Vtg = (_Float16*)(ws + 32 * MB);  // [32][64][2048] 8 MB (sigma cols)
    _Float16* AO  = (_Float16*)(ws + 40 * MB);  // [4096][1024]   8 MB

    prep_kernel<<<8192, 256, 0, stream>>>(x, Wqkv, Wproj, Xh, Wqt, Wpt);
    gemm_qkv<<<192, 512, 0, stream>>>(Xh, Wqt, bqkv, Qg, Kg, Vtg);
    attn_kernel<<<dim3(32, 16), 512, 0, stream>>>(Qg, Kg, Vtg, AO);
    gemm_proj<<<dim3(8, 64), 256, 0, stream>>>(AO, Wpt, bproj, out);
}

// Round 7
// 174.579 us; speedup vs baseline: 1.1558x; 1.1558x over previous
//
#include <hip/hip_runtime.h>

typedef _Float16 half8 __attribute__((ext_vector_type(8)));
typedef _Float16 half4 __attribute__((ext_vector_type(4)));
typedef _Float16 half2 __attribute__((ext_vector_type(2)));
typedef float f32x4 __attribute__((ext_vector_type(4)));
typedef unsigned int u32x4 __attribute__((ext_vector_type(4)));

#define MFMA16(a, b, c) __builtin_amdgcn_mfma_f32_16x16x32_f16((a), (b), (c), 0, 0, 0)
#define EXP2F(x) __builtin_amdgcn_exp2f(x)

#define GLOBAL_LOAD_LDS16(gptr, lptr)                                        \
    __builtin_amdgcn_global_load_lds(                                        \
        (const __attribute__((address_space(1))) void*)(gptr),               \
        (__attribute__((address_space(3))) void*)(lptr), 16, 0, 0)

// Q is pre-scaled by softmax_scale * log2(e) in the qkv epilogue.
#define QSCALE 0.18033688f  // 0.125 * log2(e)

#define SCHED0() __builtin_amdgcn_sched_barrier(0)
#define BARRIER() do { SCHED0(); asm volatile("" ::: "memory");            \
                       __builtin_amdgcn_s_barrier();                        \
                       asm volatile("" ::: "memory"); SCHED0(); } while (0)
#define WAITV(N) asm volatile("s_waitcnt vmcnt(" #N ")" ::: "memory")

// ---------------- fused prep: cast x + transpose-cast both weights ----------------

__global__ __launch_bounds__(256) void prep_kernel(const float* __restrict__ x,
                                                   const float* __restrict__ Wqkv,
                                                   const float* __restrict__ Wproj,
                                                   _Float16* __restrict__ Xh,
                                                   _Float16* __restrict__ Wqt,
                                                   _Float16* __restrict__ Wpt) {
    const int bid = blockIdx.x;
    const int tid = threadIdx.x;
    if (bid < 4096) {
        int i = bid * 1024 + tid * 4;
        float4 v = *(const float4*)(x + i);
        half4 h = {(_Float16)v.x, (_Float16)v.y, (_Float16)v.z, (_Float16)v.w};
        *(half4*)(Xh + i) = h;
        return;
    }
    __shared__ _Float16 tile[32][33];
    const float* W;
    _Float16* Wt;
    int n0, k0, N;
    if (bid < 7168) {
        int t = bid - 4096;
        W = Wqkv; Wt = Wqt; N = 3072;
        n0 = (t % 96) * 32; k0 = (t / 96) * 32;
    } else {
        int t = bid - 7168;
        W = Wproj; Wt = Wpt; N = 1024;
        n0 = (t & 31) * 32; k0 = (t >> 5) * 32;
    }
    int c = tid & 31, r4 = tid >> 5;
    for (int i = 0; i < 4; i++) {
        int r = r4 + i * 8;
        tile[r][c] = (_Float16)W[(k0 + r) * N + n0 + c];
    }
    __syncthreads();
    for (int i = 0; i < 4; i++) {
        int r = r4 + i * 8;  // n within tile
        Wt[(n0 + r) * 1024 + k0 + c] = tile[c][r];
    }
}

// ---------------- QKV GEMM: 256x256-tile 8-phase counted-vmcnt (T2+T3+T4+T5) ----------------

#define LOFF(ROW, Q) ((((ROW) >> 1) * 64) + \
    ((((((ROW) & 1) << 2) | (Q)) ^ (((ROW) >> 1) & 7)) * 8))

__global__ __launch_bounds__(512) void gemm_qkv(const _Float16* __restrict__ A,
                                                const _Float16* __restrict__ Bt,
                                                const float* __restrict__ bias,
                                                _Float16* __restrict__ Qo,
                                                _Float16* __restrict__ Ko,
                                                _Float16* __restrict__ Vto) {
    __shared__ _Float16 L[65536];  // [buf2][op2][kk2][8192 halfs] = 128 KB
    const int tid = threadIdx.x;
    const int lin = blockIdx.x;
    const int xcd = lin & 7, slot = lin >> 3;      // slot 0..23
    const int m0 = (xcd * 2 + slot / 12) * 256;    // 16 m-tiles
    const int n0 = (slot % 12) * 256;              // 12 n-tiles
    const int wave = tid >> 6, lane = tid & 63;
    const int wm = wave >> 2, wn = wave & 3;       // 2M x 4N waves
    const int quad = lane >> 4, l15 = lane & 15;

    // staging: linear GLL dest (lane*16B), pre-swizzled global source
    const int s8 = (tid & 7) ^ ((tid >> 3) & 7);   // logical 16B-slot (0..7)
    const int srow = (tid >> 3) * 2 + (s8 >> 2);   // logical row (round 0)
    const int scol = (s8 & 3) * 8;                 // logical col within kk-half
    const _Float16* Asrc = A + (size_t)(m0 + srow) * 1024 + scol;
    const _Float16* Bsrc = Bt + (size_t)(n0 + srow) * 1024 + scol;
    _Float16* Ldst = L + tid * 8;

#define STG(OP, KK, KT) do {                                                  \
    const _Float16* _g = ((OP) ? Bsrc : Asrc) + ((KT) & 15) * 64 + (KK) * 32; \
    _Float16* _l = Ldst + ((KT) & 1) * 32768 + (OP) * 16384 + (KK) * 8192;    \
    GLOBAL_LOAD_LDS16(_g, _l);                                                \
    GLOBAL_LOAD_LDS16(_g + 128 * 1024, _l + 4096);                            \
} while (0)

    const int arow = wm * 128 + l15;   // + MH*64 + fi*16
    const int brow = wn * 64 + l15;    // + nf*16

    f32x4 acc[8][4] = {};
    half8 af[4], bf[4];

#define PHASE(BUF, KK, MH, RDB, SOP, SKK, SKT, W4) do {                        \
    const _Float16* _ab = L + (BUF) * 32768 + (KK) * 8192;                     \
    const _Float16* _bb = _ab + 16384;                                         \
    if (RDB) {                                                                 \
        _Pragma("unroll") for (int nf = 0; nf < 4; nf++)                       \
            bf[nf] = *(const half8*)(_bb + LOFF(brow + nf * 16, quad));        \
    }                                                                          \
    _Pragma("unroll") for (int fi = 0; fi < 4; fi++)                           \
        af[fi] = *(const half8*)(_ab + LOFF(arow + (MH) * 64 + fi * 16, quad));\
    STG(SOP, SKK, SKT);                                                        \
    BARRIER();                                                                 \
    __builtin_amdgcn_s_setprio(1);                                             \
    _Pragma("unroll") for (int fi = 0; fi < 4; fi++)                           \
        _Pragma("unroll") for (int nf = 0; nf < 4; nf++)                       \
            acc[(MH) * 4 + fi][nf] = MFMA16(af[fi], bf[nf],                    \
                                            acc[(MH) * 4 + fi][nf]);           \
    __builtin_amdgcn_s_setprio(0);                                             \
    if (W4) { WAITV(4); }                                                      \
    BARRIER();                                                                 \
} while (0)

    // prologue: tile0 complete + tile1 lo-halves in flight
    STG(0, 0, 0); STG(1, 0, 0); STG(0, 1, 0); STG(1, 1, 0);
    STG(0, 0, 1); STG(1, 0, 1);
    WAITV(4);           // tile0's 8 loads done; tile1 lo (4 loads) in flight
    BARRIER();

    for (int i = 0; i < 8; ++i) {
        const int ta = 2 * i, tb = 2 * i + 1;
        PHASE(0, 0, 0, 1, 0, 1, tb,     0);  // p1: +stage A-hi(t+1)
        PHASE(0, 0, 1, 0, 1, 1, tb,     0);  // p2: +stage B-hi(t+1)
        PHASE(0, 1, 0, 1, 0, 0, ta + 2, 0);  // p3: +stage A-lo(t+2)
        PHASE(0, 1, 1, 0, 1, 0, ta + 2, 1);  // p4: +stage B-lo(t+2); vmcnt(4)
        PHASE(1, 0, 0, 1, 0, 1, ta + 2, 0);  // p5: +stage A-hi(t+2)
        PHASE(1, 0, 1, 0, 1, 1, ta + 2, 0);  // p6: +stage B-hi(t+2)
        PHASE(1, 1, 0, 1, 0, 0, tb + 2, 0);  // p7: +stage A-lo(t+3)
        PHASE(1, 1, 1, 0, 1, 0, tb + 2, 1);  // p8: +stage B-lo(t+3); vmcnt(4)
    }
    WAITV(0);  // drain trailing (wrapped) stages before epilogue / endpgm

    // epilogue: scatter to Q (scaled) / K / Vt. which is block-uniform.
    // V columns are stored SIGMA-PERMUTED within each 32-t block:
    //   t = 16h + 4q + r  ->  p = (t & ~31) | (q<<3) | (h<<2) | r
    // so attn's PV B-operand (native P pack) and V agree on k with a plain
    // contiguous LDS copy (no swizzled LDS stores -> no bank conflicts).
    const int which = n0 >> 10;
    const int hh = ((n0 + wn * 64) & 1023) >> 6;  // head idx (wave-uniform)
    float bv[4];
    const int gnb = n0 + wn * 64;
#pragma unroll
    for (int nf = 0; nf < 4; nf++) bv[nf] = bias[gnb + nf * 16 + l15];

#pragma unroll
    for (int mf = 0; mf < 8; mf++) {
        const int gm0 = m0 + wm * 128 + mf * 16 + quad * 4;
        const int b = gm0 >> 11, t0 = gm0 & 2047;
        const int bh = b * 16 + hh;
#pragma unroll
        for (int nf = 0; nf < 4; nf++) {
            const int dh = nf * 16 + l15;
            if (which == 2) {
                half4 hv;
#pragma unroll
                for (int r = 0; r < 4; r++)
                    hv[r] = (_Float16)(acc[mf][nf][r] + bv[nf]);
                const int p0 = (t0 & ~31) | (((t0 >> 2) & 3) << 3) | (((t0 >> 4) & 1) << 2);
                *(half4*)(&Vto[(size_t)(bh * 64 + dh) * 2048 + p0]) = hv;
            } else if (which == 0) {
#pragma unroll
                for (int r = 0; r < 4; r++)
                    Qo[((size_t)bh * 2048 + t0 + r) * 64 + dh] =
                        (_Float16)((acc[mf][nf][r] + bv[nf]) * QSCALE);
            } else {
#pragma unroll
                for (int r = 0; r < 4; r++)
                    Ko[((size_t)bh * 2048 + t0 + r) * 64 + dh] =
                        (_Float16)(acc[mf][nf][r] + bv[nf]);
            }
        }
    }
#undef PHASE
#undef STG
}

// ---------------- flash attention R7: g=4 (64q/wave), KVBLK=64, all-GLL staging ----------------
// R6 regressed (scattered global K loads = TA/VMEM-bound). R7 keeps K AND V in
// LDS via global_load_lds, but raises per-LDS-read MFMA reuse 2->4: each wave
// owns 64 q (g=4) x half the k-columns (kh). 256 threads = 2 pw x 2 kh waves,
// KV tile 64, dbuf 32 KB, 1 barrier/tile. Both K and V use T21: linear GLL
// dest + XOR-pre-swizzled global source + XOR-swizzled read (conflict-free;
// V additionally carries the sigma column permutation in its global layout).
// Per-CU LDS read instrs halve vs R5; ds_writes eliminated.

static __device__ inline unsigned pk2(float a, float b) {
    half2 p;
    p.x = (_Float16)a;
    p.y = (_Float16)b;
    return __builtin_bit_cast(unsigned, p);
}

__global__ __launch_bounds__(256, 2) void attn_kernel(const _Float16* __restrict__ Qg,
                                                      const _Float16* __restrict__ Kg,
                                                      const _Float16* __restrict__ Vtg,
                                                      _Float16* __restrict__ AO) {
    __shared__ __align__(16) _Float16 Lsh[2][8192];  // [buf][K 4096 | V 4096] = 32 KB

    const int tid = threadIdx.x;
    const int bh = blockIdx.x;
    const int q0 = blockIdx.y * 128;
    const int b = bh >> 4, h = bh & 15;
    const int wave = tid >> 6, lane = tid & 63;
    const int pw = wave & 1;     // q half: rows [pw*64, +64)
    const int kh = wave >> 1;    // k half of the 64-tile: [kh*32, +32)
    const int quad = lane >> 4, l15 = lane & 15;
    const int akey = l15 & 7;

    half8 qf[4][2];
#pragma unroll
    for (int g = 0; g < 4; g++) {
        const int qrow = q0 + pw * 64 + g * 16 + l15;
#pragma unroll
        for (int kk = 0; kk < 2; kk++)
            qf[g][kk] = *(const half8*)(&Qg[(bh * 2048 + qrow) * 64 + kk * 32 + quad * 8]);
    }

    const _Float16* Kbase = Kg + (size_t)bh * 2048 * 64;
    const _Float16* Vbase = Vtg + (size_t)bh * 64 * 2048;

    // GLL staging: linear dest (tid*16B), pre-swizzled global source.
    // K: row = t-within-tile (64), col = dh. V: row = d (64), col = t-in-tile.
    const int srow = tid >> 3, sc8 = tid & 7;
    const int scol = (sc8 ^ (srow & 7)) * 8;       // (srow+32)&7 == srow&7
    const _Float16* Ksrc = Kbase + (size_t)srow * 64 + scol;
    const _Float16* Vsrc = Vbase + (size_t)srow * 2048 + scol;

#define STAGE(BUF, KT) do {                                                    \
    const size_t _ko = (size_t)(KT) * 4096;                                    \
    const int _vo = (KT) * 64;                                                 \
    GLOBAL_LOAD_LDS16(Ksrc + _ko,              &Lsh[BUF][tid * 8]);            \
    GLOBAL_LOAD_LDS16(Ksrc + _ko + 2048,       &Lsh[BUF][2048 + tid * 8]);     \
    GLOBAL_LOAD_LDS16(Vsrc + _vo,              &Lsh[BUF][4096 + tid * 8]);     \
    GLOBAL_LOAD_LDS16(Vsrc + _vo + 32 * 2048,  &Lsh[BUF][6144 + tid * 8]);     \
} while (0)

    f32x4 oacc[4][4] = {};
    float lsum[4] = {0.f, 0.f, 0.f, 0.f};

    STAGE(0, 0);
    WAITV(0);
    BARRIER();

    for (int kt = 0; kt < 32; kt++) {
        const int cur = kt & 1;
        STAGE(cur ^ 1, (kt + 1) & 31);

        const _Float16* Kb = &Lsh[cur][0];
        const _Float16* Vb = &Lsh[cur][4096];
        const int r0 = kh * 32 + l15;        // k-16-block j=0
        const int r1 = kh * 32 + 16 + l15;   // k-16-block j=1
        half8 kaa = *(const half8*)(Kb + r0 * 64 + (quad ^ akey) * 8);
        half8 kab = *(const half8*)(Kb + r0 * 64 + ((quad + 4) ^ akey) * 8);
        half8 kba = *(const half8*)(Kb + r1 * 64 + (quad ^ akey) * 8);
        half8 kbb = *(const half8*)(Kb + r1 * 64 + ((quad + 4) ^ akey) * 8);
        half8 av[4];
#pragma unroll
        for (int di = 0; di < 4; di++)
            av[di] = *(const half8*)(Vb + (di * 16 + l15) * 64 +
                                     ((kh * 4 + quad) ^ akey) * 8);

#pragma unroll
        for (int g = 0; g < 4; g++) {
            f32x4 sA = {}, sB = {};
            sA = MFMA16(kaa, qf[g][0], sA);
            sA = MFMA16(kab, qf[g][1], sA);
            sB = MFMA16(kba, qf[g][0], sB);
            sB = MFMA16(kbb, qf[g][1], sB);
            float a0 = EXP2F(sA[0]), a1 = EXP2F(sA[1]);
            float a2 = EXP2F(sA[2]), a3 = EXP2F(sA[3]);
            float b0 = EXP2F(sB[0]), b1 = EXP2F(sB[1]);
            float b2 = EXP2F(sB[2]), b3 = EXP2F(sB[3]);
            lsum[g] += ((a0 + a1) + (a2 + a3)) + ((b0 + b1) + (b2 + b3));
            u32x4 w = {pk2(a0, a1), pk2(a2, a3), pk2(b0, b1), pk2(b2, b3)};
            half8 bP = __builtin_bit_cast(half8, w);
#pragma unroll
            for (int di = 0; di < 4; di++)
                oacc[g][di] = MFMA16(av[di], bP, oacc[g][di]);
        }

        WAITV(0);
        BARRIER();
    }
#undef STAGE

    // quad-reduce lsum (each lane held its quad's 8-k partial)
#pragma unroll
    for (int g = 0; g < 4; g++) {
        lsum[g] += __shfl_xor(lsum[g], 16, 64);
        lsum[g] += __shfl_xor(lsum[g], 32, 64);
    }

    // ---- cross-wave (kh) combine: partials are pure sums. Two passes. ----
    float* cb = (float*)&Lsh[0][0];      // 4096 floats (16 KB)
    float* lb = cb + 4096;               // 512 floats (in Lsh[1])
    const int pid = pw * 64 + lane;      // 0..127, lane-major -> conflict-free

    __syncthreads();
    if (kh == 1) {
#pragma unroll
        for (int g = 0; g < 2; g++)
#pragma unroll
            for (int di = 0; di < 4; di++)
#pragma unroll
                for (int j = 0; j < 4; j++)
                    cb[(((g << 2) | di) * 4 + j) * 128 + pid] = oacc[g][di][j];
#pragma unroll
        for (int g = 0; g < 4; g++) lb[pid * 4 + g] = lsum[g];
    }
    __syncthreads();
    if (kh == 0) {
#pragma unroll
        for (int g = 0; g < 2; g++)
#pragma unroll
            for (int di = 0; di < 4; di++)
#pragma unroll
                for (int j = 0; j < 4; j++)
                    oacc[g][di][j] += cb[(((g << 2) | di) * 4 + j) * 128 + pid];
#pragma unroll
        for (int g = 0; g < 4; g++) lsum[g] += lb[pid * 4 + g];
    }
    __syncthreads();
    if (kh == 1) {
#pragma unroll
        for (int g = 2; g < 4; g++)
#pragma unroll
            for (int di = 0; di < 4; di++)
#pragma unroll
                for (int j = 0; j < 4; j++)
                    cb[((((g - 2) << 2) | di) * 4 + j) * 128 + pid] = oacc[g][di][j];
    }
    __syncthreads();
    if (kh == 0) {
#pragma unroll
        for (int g = 2; g < 4; g++)
#pragma unroll
            for (int di = 0; di < 4; di++)
#pragma unroll
                for (int j = 0; j < 4; j++)
                    oacc[g][di][j] += cb[((((g - 2) << 2) | di) * 4 + j) * 128 + pid];

        for (int g = 0; g < 4; g++) {
            float inv = 1.f / lsum[g];
            const int qrow = q0 + pw * 64 + g * 16 + l15;
            for (int di = 0; di < 4; di++) {
                half4 hv;
                hv[0] = (_Float16)(oacc[g][di][0] * inv);
                hv[1] = (_Float16)(oacc[g][di][1] * inv);
                hv[2] = (_Float16)(oacc[g][di][2] * inv);
                hv[3] = (_Float16)(oacc[g][di][3] * inv);
                *(half4*)(&AO[(size_t)(b * 2048 + qrow) * 1024 + h * 64 + di * 16 + quad * 4]) = hv;
            }
        }
    }
}

// ---------------- proj GEMM: out[4096,1024] = AO @ Wp + bp (fp32 out) ----------------

__global__ __launch_bounds__(256) void gemm_proj(const _Float16* __restrict__ A,
                                                 const _Float16* __restrict__ Bt,
                                                 const float* __restrict__ bias,
                                                 float* __restrict__ out) {
    __shared__ _Float16 As[64][64];    //  8 KB
    __shared__ _Float16 Bs[128][64];   // 16 KB
    const int tid = threadIdx.x;
    const int lin = blockIdx.x + 8 * blockIdx.y;
    const int xcd = lin & 7, slot = lin >> 3;     // slot 0..63
    const int n0 = (slot >> 3) * 128;
    const int m0 = (xcd * 8 + (slot & 7)) * 64;
    const int wave = tid >> 6, lane = tid & 63;
    const int quad = lane >> 4, l15 = lane & 15;
    const int sw = l15 & 7;
    const int ldrowA = wave * 16 + (lane >> 3);
    const int ldrowB = wave * 32 + (lane >> 3);
    const int ldslot = (lane & 7) * 8;
    const int gcolA = (((lane & 7) ^ (ldrowA & 7))) * 8;
    const int gcolB = (((lane & 7) ^ (ldrowB & 7))) * 8;

    f32x4 acc[4][2] = {};
    for (int k0 = 0; k0 < 1024; k0 += 64) {
        __syncthreads();
        for (int i = 0; i < 2; i++) {
            int r = ldrowA + i * 8;
            GLOBAL_LOAD_LDS16(&A[(size_t)(m0 + r) * 1024 + k0 + gcolA], &As[r][ldslot]);
        }
        for (int i = 0; i < 4; i++) {
            int r = ldrowB + i * 8;
            GLOBAL_LOAD_LDS16(&Bt[(size_t)(n0 + r) * 1024 + k0 + gcolB], &Bs[r][ldslot]);
        }
        __syncthreads();
        for (int kk = 0; kk < 64; kk += 32) {
            const int rcol = (((kk >> 3) + quad) ^ sw) * 8;
            half8 af[4], bf[2];
            for (int mi = 0; mi < 4; mi++)
                af[mi] = *(const half8*)(&As[mi * 16 + l15][rcol]);
            for (int ni = 0; ni < 2; ni++)
                bf[ni] = *(const half8*)(&Bs[wave * 32 + ni * 16 + l15][rcol]);
            for (int mi = 0; mi < 4; mi++)
                for (int ni = 0; ni < 2; ni++)
                    acc[mi][ni] = MFMA16(af[mi], bf[ni], acc[mi][ni]);
        }
    }
    for (int mi = 0; mi < 4; mi++)
        for (int ni = 0; ni < 2; ni++) {
            int gn = n0 + wave * 32 + ni * 16 + l15;
            float bv = bias[gn];
            for (int r = 0; r < 4; r++) {
                int gm = m0 + mi * 16 + quad * 4 + r;
                out[(size_t)gm * 1024 + gn] = acc[mi][ni][r] + bv;
            }
        }
}

// ---------------- launch ----------------

extern "C" void kernel_launch(void* const* d_in, const int* in_sizes, int n_in,
                              void* d_out, int out_size, void* d_ws, size_t ws_size,
                              hipStream_t stream) {
    const float* x     = (const float*)d_in[0];
    const float* Wqkv  = (const float*)d_in[1];
    const float* bqkv  = (const float*)d_in[2];
    const float* Wproj = (const float*)d_in[3];
    const float* bproj = (const float*)d_in[4];
    float* out = (float*)d_out;

    char* ws = (char*)d_ws;
    const size_t MB = 1024 * 1024;
    _Float16* Xh  = (_Float16*)(ws + 0 * MB);   // [4096][1024]   8 MB
    _Float16* Wqt = (_Float16*)(ws + 8 * MB);   // [3072][1024]   6 MB
    _Float16* Wpt = (_Float16*)(ws + 14 * MB);  // [1024][1024]   2 MB
    _Float16* Qg  = (_Float16*)(ws + 16 * MB);  // [32][2048][64] 8 MB (pre-scaled)
    _Float16* Kg  = (_Float16*)(ws + 24 * MB);  // [32][2048][64] 8 MB
    _Float16* Vtg = (_Float16*)(ws + 32 * MB);  // [32][64][2048] 8 MB (sigma cols)
    _Float16* AO  = (_Float16*)(ws + 40 * MB);  // [4096][1024]   8 MB

    prep_kernel<<<8192, 256, 0, stream>>>(x, Wqkv, Wproj, Xh, Wqt, Wpt);
    gemm_qkv<<<192, 512, 0, stream>>>(Xh, Wqt, bqkv, Qg, Kg, Vtg);
    attn_kernel<<<dim3(32, 16), 256, 0, stream>>>(Qg, Kg, Vtg, AO);
    gemm_proj<<<dim3(8, 64), 256, 0, stream>>>(AO, Wpt, bproj, out);
}

// Round 8
// 173.779 us; speedup vs baseline: 1.1611x; 1.0046x over previous
//
#include <hip/hip_runtime.h>

typedef _Float16 half8 __attribute__((ext_vector_type(8)));
typedef _Float16 half4 __attribute__((ext_vector_type(4)));
typedef _Float16 half2 __attribute__((ext_vector_type(2)));
typedef float f32x4 __attribute__((ext_vector_type(4)));
typedef unsigned int u32x4 __attribute__((ext_vector_type(4)));

#define MFMA16(a, b, c) __builtin_amdgcn_mfma_f32_16x16x32_f16((a), (b), (c), 0, 0, 0)
#define EXP2F(x) __builtin_amdgcn_exp2f(x)

#define GLOBAL_LOAD_LDS16(gptr, lptr)                                        \
    __builtin_amdgcn_global_load_lds(                                        \
        (const __attribute__((address_space(1))) void*)(gptr),               \
        (__attribute__((address_space(3))) void*)(lptr), 16, 0, 0)

// Q is pre-scaled by softmax_scale * log2(e) in the qkv epilogue.
#define QSCALE 0.18033688f  // 0.125 * log2(e)

#define SCHED0() __builtin_amdgcn_sched_barrier(0)
#define BARRIER() do { SCHED0(); asm volatile("" ::: "memory");            \
                       __builtin_amdgcn_s_barrier();                        \
                       asm volatile("" ::: "memory"); SCHED0(); } while (0)
#define WAITV(N) asm volatile("s_waitcnt vmcnt(" #N ")" ::: "memory")

// ---------------- fused prep: cast x + transpose-cast both weights ----------------

__global__ __launch_bounds__(256) void prep_kernel(const float* __restrict__ x,
                                                   const float* __restrict__ Wqkv,
                                                   const float* __restrict__ Wproj,
                                                   _Float16* __restrict__ Xh,
                                                   _Float16* __restrict__ Wqt,
                                                   _Float16* __restrict__ Wpt) {
    const int bid = blockIdx.x;
    const int tid = threadIdx.x;
    if (bid < 4096) {
        int i = bid * 1024 + tid * 4;
        float4 v = *(const float4*)(x + i);
        half4 h = {(_Float16)v.x, (_Float16)v.y, (_Float16)v.z, (_Float16)v.w};
        *(half4*)(Xh + i) = h;
        return;
    }
    __shared__ _Float16 tile[32][33];
    const float* W;
    _Float16* Wt;
    int n0, k0, N;
    if (bid < 7168) {
        int t = bid - 4096;
        W = Wqkv; Wt = Wqt; N = 3072;
        n0 = (t % 96) * 32; k0 = (t / 96) * 32;
    } else {
        int t = bid - 7168;
        W = Wproj; Wt = Wpt; N = 1024;
        n0 = (t & 31) * 32; k0 = (t >> 5) * 32;
    }
    int c = tid & 31, r4 = tid >> 5;
    for (int i = 0; i < 4; i++) {
        int r = r4 + i * 8;
        tile[r][c] = (_Float16)W[(k0 + r) * N + n0 + c];
    }
    __syncthreads();
    for (int i = 0; i < 4; i++) {
        int r = r4 + i * 8;  // n within tile
        Wt[(n0 + r) * 1024 + k0 + c] = tile[c][r];
    }
}

// ---------------- QKV GEMM: 256x256-tile 8-phase counted-vmcnt (T2+T3+T4+T5) ----------------

#define LOFF(ROW, Q) ((((ROW) >> 1) * 64) + \
    ((((((ROW) & 1) << 2) | (Q)) ^ (((ROW) >> 1) & 7)) * 8))

__global__ __launch_bounds__(512) void gemm_qkv(const _Float16* __restrict__ A,
                                                const _Float16* __restrict__ Bt,
                                                const float* __restrict__ bias,
                                                _Float16* __restrict__ Qo,
                                                _Float16* __restrict__ Ko,
                                                _Float16* __restrict__ Vto) {
    __shared__ _Float16 L[65536];  // [buf2][op2][kk2][8192 halfs] = 128 KB
    const int tid = threadIdx.x;
    const int lin = blockIdx.x;
    const int xcd = lin & 7, slot = lin >> 3;      // slot 0..23
    const int m0 = (xcd * 2 + slot / 12) * 256;    // 16 m-tiles
    const int n0 = (slot % 12) * 256;              // 12 n-tiles
    const int wave = tid >> 6, lane = tid & 63;
    const int wm = wave >> 2, wn = wave & 3;       // 2M x 4N waves
    const int quad = lane >> 4, l15 = lane & 15;

    // staging: linear GLL dest (lane*16B), pre-swizzled global source
    const int s8 = (tid & 7) ^ ((tid >> 3) & 7);   // logical 16B-slot (0..7)
    const int srow = (tid >> 3) * 2 + (s8 >> 2);   // logical row (round 0)
    const int scol = (s8 & 3) * 8;                 // logical col within kk-half
    const _Float16* Asrc = A + (size_t)(m0 + srow) * 1024 + scol;
    const _Float16* Bsrc = Bt + (size_t)(n0 + srow) * 1024 + scol;
    _Float16* Ldst = L + tid * 8;

#define STG(OP, KK, KT) do {                                                  \
    const _Float16* _g = ((OP) ? Bsrc : Asrc) + ((KT) & 15) * 64 + (KK) * 32; \
    _Float16* _l = Ldst + ((KT) & 1) * 32768 + (OP) * 16384 + (KK) * 8192;    \
    GLOBAL_LOAD_LDS16(_g, _l);                                                \
    GLOBAL_LOAD_LDS16(_g + 128 * 1024, _l + 4096);                            \
} while (0)

    const int arow = wm * 128 + l15;   // + MH*64 + fi*16
    const int brow = wn * 64 + l15;    // + nf*16

    f32x4 acc[8][4] = {};
    half8 af[4], bf[4];

#define PHASE(BUF, KK, MH, RDB, SOP, SKK, SKT, W4) do {                        \
    const _Float16* _ab = L + (BUF) * 32768 + (KK) * 8192;                     \
    const _Float16* _bb = _ab + 16384;                                         \
    if (RDB) {                                                                 \
        _Pragma("unroll") for (int nf = 0; nf < 4; nf++)                       \
            bf[nf] = *(const half8*)(_bb + LOFF(brow + nf * 16, quad));        \
    }                                                                          \
    _Pragma("unroll") for (int fi = 0; fi < 4; fi++)                           \
        af[fi] = *(const half8*)(_ab + LOFF(arow + (MH) * 64 + fi * 16, quad));\
    STG(SOP, SKK, SKT);                                                        \
    BARRIER();                                                                 \
    __builtin_amdgcn_s_setprio(1);                                             \
    _Pragma("unroll") for (int fi = 0; fi < 4; fi++)                           \
        _Pragma("unroll") for (int nf = 0; nf < 4; nf++)                       \
            acc[(MH) * 4 + fi][nf] = MFMA16(af[fi], bf[nf],                    \
                                            acc[(MH) * 4 + fi][nf]);           \
    __builtin_amdgcn_s_setprio(0);                                             \
    if (W4) { WAITV(4); }                                                      \
    BARRIER();                                                                 \
} while (0)

    // prologue: tile0 complete + tile1 lo-halves in flight
    STG(0, 0, 0); STG(1, 0, 0); STG(0, 1, 0); STG(1, 1, 0);
    STG(0, 0, 1); STG(1, 0, 1);
    WAITV(4);           // tile0's 8 loads done; tile1 lo (4 loads) in flight
    BARRIER();

    for (int i = 0; i < 8; ++i) {
        const int ta = 2 * i, tb = 2 * i + 1;
        PHASE(0, 0, 0, 1, 0, 1, tb,     0);  // p1: +stage A-hi(t+1)
        PHASE(0, 0, 1, 0, 1, 1, tb,     0);  // p2: +stage B-hi(t+1)
        PHASE(0, 1, 0, 1, 0, 0, ta + 2, 0);  // p3: +stage A-lo(t+2)
        PHASE(0, 1, 1, 0, 1, 0, ta + 2, 1);  // p4: +stage B-lo(t+2); vmcnt(4)
        PHASE(1, 0, 0, 1, 0, 1, ta + 2, 0);  // p5: +stage A-hi(t+2)
        PHASE(1, 0, 1, 0, 1, 1, ta + 2, 0);  // p6: +stage B-hi(t+2)
        PHASE(1, 1, 0, 1, 0, 0, tb + 2, 0);  // p7: +stage A-lo(t+3)
        PHASE(1, 1, 1, 0, 1, 0, tb + 2, 1);  // p8: +stage B-lo(t+3); vmcnt(4)
    }
    WAITV(0);  // drain trailing (wrapped) stages before epilogue / endpgm

    // epilogue: scatter to Q (scaled) / K / Vt. which is block-uniform.
    // V columns are stored SIGMA-PERMUTED within each 32-t block:
    //   t = 16h + 4q + r  ->  p = (t & ~31) | (q<<3) | (h<<2) | r
    // so attn's PV B-operand (native P pack) and V agree on k with a plain
    // contiguous LDS copy (no swizzled LDS stores -> no bank conflicts).
    const int which = n0 >> 10;
    const int hh = ((n0 + wn * 64) & 1023) >> 6;  // head idx (wave-uniform)
    float bv[4];
    const int gnb = n0 + wn * 64;
#pragma unroll
    for (int nf = 0; nf < 4; nf++) bv[nf] = bias[gnb + nf * 16 + l15];

#pragma unroll
    for (int mf = 0; mf < 8; mf++) {
        const int gm0 = m0 + wm * 128 + mf * 16 + quad * 4;
        const int b = gm0 >> 11, t0 = gm0 & 2047;
        const int bh = b * 16 + hh;
#pragma unroll
        for (int nf = 0; nf < 4; nf++) {
            const int dh = nf * 16 + l15;
            if (which == 2) {
                half4 hv;
#pragma unroll
                for (int r = 0; r < 4; r++)
                    hv[r] = (_Float16)(acc[mf][nf][r] + bv[nf]);
                const int p0 = (t0 & ~31) | (((t0 >> 2) & 3) << 3) | (((t0 >> 4) & 1) << 2);
                *(half4*)(&Vto[(size_t)(bh * 64 + dh) * 2048 + p0]) = hv;
            } else if (which == 0) {
#pragma unroll
                for (int r = 0; r < 4; r++)
                    Qo[((size_t)bh * 2048 + t0 + r) * 64 + dh] =
                        (_Float16)((acc[mf][nf][r] + bv[nf]) * QSCALE);
            } else {
#pragma unroll
                for (int r = 0; r < 4; r++)
                    Ko[((size_t)bh * 2048 + t0 + r) * 64 + dh] =
                        (_Float16)(acc[mf][nf][r] + bv[nf]);
            }
        }
    }
#undef PHASE
#undef STG
}

// ---------------- flash attention R8: g=4, KVBLK=64, 3-ring + counted vmcnt ----------------
// R7's structure (g=4 reuse, all-GLL staging, 0 conflicts) kept; the per-tile
// WAITV(0) drain is replaced by a 3-deep ring with counted WAITV(4) (T3/T4):
// stage tile t+2 at iter t; after compute wait only for tile t+1's 4 loads
// (tile t+2's stay in flight across the barrier). Each tile's loads get a full
// iteration (~1.5K cyc) to land -> no exposed L2 latency per iteration.
// Wrapped stages at kt=30/31 keep the vmcnt ledger uniform; WAITV(0) before
// the combine drains them. LDS 48 KB, 2 blocks/CU. setprio around MFMA (T5).

static __device__ inline unsigned pk2(float a, float b) {
    half2 p;
    p.x = (_Float16)a;
    p.y = (_Float16)b;
    return __builtin_bit_cast(unsigned, p);
}

__global__ __launch_bounds__(256, 2) void attn_kernel(const _Float16* __restrict__ Qg,
                                                      const _Float16* __restrict__ Kg,
                                                      const _Float16* __restrict__ Vtg,
                                                      _Float16* __restrict__ AO) {
    __shared__ __align__(16) _Float16 Lsh[3][8192];  // [ring][K 4096 | V 4096] = 48 KB

    const int tid = threadIdx.x;
    const int bh = blockIdx.x;
    const int q0 = blockIdx.y * 128;
    const int b = bh >> 4, h = bh & 15;
    const int wave = tid >> 6, lane = tid & 63;
    const int pw = wave & 1;     // q half: rows [pw*64, +64)
    const int kh = wave >> 1;    // k half of the 64-tile: [kh*32, +32)
    const int quad = lane >> 4, l15 = lane & 15;
    const int akey = l15 & 7;

    half8 qf[4][2];
#pragma unroll
    for (int g = 0; g < 4; g++) {
        const int qrow = q0 + pw * 64 + g * 16 + l15;
#pragma unroll
        for (int kk = 0; kk < 2; kk++)
            qf[g][kk] = *(const half8*)(&Qg[(bh * 2048 + qrow) * 64 + kk * 32 + quad * 8]);
    }

    const _Float16* Kbase = Kg + (size_t)bh * 2048 * 64;
    const _Float16* Vbase = Vtg + (size_t)bh * 64 * 2048;

    // GLL staging: linear dest (tid*16B), pre-swizzled global source.
    const int srow = tid >> 3, sc8 = tid & 7;
    const int scol = (sc8 ^ (srow & 7)) * 8;       // (srow+32)&7 == srow&7
    const _Float16* Ksrc = Kbase + (size_t)srow * 64 + scol;
    const _Float16* Vsrc = Vbase + (size_t)srow * 2048 + scol;

#define STAGE(BUF, KT) do {                                                    \
    const size_t _ko = (size_t)(KT) * 4096;                                    \
    const int _vo = (KT) * 64;                                                 \
    _Float16* _lb = &Lsh[BUF][0];                                              \
    GLOBAL_LOAD_LDS16(Ksrc + _ko,              _lb + tid * 8);                 \
    GLOBAL_LOAD_LDS16(Ksrc + _ko + 2048,       _lb + 2048 + tid * 8);          \
    GLOBAL_LOAD_LDS16(Vsrc + _vo,              _lb + 4096 + tid * 8);          \
    GLOBAL_LOAD_LDS16(Vsrc + _vo + 32 * 2048,  _lb + 6144 + tid * 8);          \
} while (0)

    f32x4 oacc[4][4] = {};
    float lsum[4] = {0.f, 0.f, 0.f, 0.f};

    // prologue: tiles 0,1 staged (tile1 stays in flight past the barrier)
    STAGE(0, 0);
    STAGE(1, 1);
    WAITV(4);        // tile0's 4 loads (and qf) done; tile1's 4 in flight
    BARRIER();

    int cur = 0;
    for (int kt = 0; kt < 32; kt++) {
        int nxt = cur + 2; if (nxt >= 3) nxt -= 3;
        STAGE(nxt, (kt + 2) & 31);          // wrapped at kt=30/31 (ledger-uniform)

        const _Float16* Kb = &Lsh[cur][0];
        const _Float16* Vb = &Lsh[cur][4096];
        const int r0 = kh * 32 + l15;        // k-16-block j=0
        const int r1 = kh * 32 + 16 + l15;   // k-16-block j=1
        half8 kaa = *(const half8*)(Kb + r0 * 64 + (quad ^ akey) * 8);
        half8 kab = *(const half8*)(Kb + r0 * 64 + ((quad + 4) ^ akey) * 8);
        half8 kba = *(const half8*)(Kb + r1 * 64 + (quad ^ akey) * 8);
        half8 kbb = *(const half8*)(Kb + r1 * 64 + ((quad + 4) ^ akey) * 8);
        half8 av[4];
#pragma unroll
        for (int di = 0; di < 4; di++)
            av[di] = *(const half8*)(Vb + (di * 16 + l15) * 64 +
                                     ((kh * 4 + quad) ^ akey) * 8);

        __builtin_amdgcn_s_setprio(1);
#pragma unroll
        for (int g = 0; g < 4; g++) {
            f32x4 sA = {}, sB = {};
            sA = MFMA16(kaa, qf[g][0], sA);
            sA = MFMA16(kab, qf[g][1], sA);
            sB = MFMA16(kba, qf[g][0], sB);
            sB = MFMA16(kbb, qf[g][1], sB);
            float a0 = EXP2F(sA[0]), a1 = EXP2F(sA[1]);
            float a2 = EXP2F(sA[2]), a3 = EXP2F(sA[3]);
            float b0 = EXP2F(sB[0]), b1 = EXP2F(sB[1]);
            float b2 = EXP2F(sB[2]), b3 = EXP2F(sB[3]);
            lsum[g] += ((a0 + a1) + (a2 + a3)) + ((b0 + b1) + (b2 + b3));
            u32x4 w = {pk2(a0, a1), pk2(a2, a3), pk2(b0, b1), pk2(b2, b3)};
            half8 bP = __builtin_bit_cast(half8, w);
#pragma unroll
            for (int di = 0; di < 4; di++)
                oacc[g][di] = MFMA16(av[di], bP, oacc[g][di]);
        }
        __builtin_amdgcn_s_setprio(0);

        WAITV(4);      // tile kt+1 landed; tile kt+2's 4 loads stay in flight
        BARRIER();
        cur = cur + 1; if (cur >= 3) cur -= 3;
    }
#undef STAGE

    // quad-reduce lsum (each lane held its quad's 8-k partial)
#pragma unroll
    for (int g = 0; g < 4; g++) {
        lsum[g] += __shfl_xor(lsum[g], 16, 64);
        lsum[g] += __shfl_xor(lsum[g], 32, 64);
    }

    WAITV(0);   // drain wrapped stages before LDS reuse
    // ---- cross-wave (kh) combine: partials are pure sums. Two passes. ----
    float* cb = (float*)&Lsh[0][0];      // 4096 floats (16 KB = ring buf 0)
    float* lb = cb + 4096;               // 512 floats (start of ring buf 1)
    const int pid = pw * 64 + lane;      // 0..127, lane-major -> conflict-free

    __syncthreads();
    if (kh == 1) {
#pragma unroll
        for (int g = 0; g < 2; g++)
#pragma unroll
            for (int di = 0; di < 4; di++)
#pragma unroll
                for (int j = 0; j < 4; j++)
                    cb[(((g << 2) | di) * 4 + j) * 128 + pid] = oacc[g][di][j];
#pragma unroll
        for (int g = 0; g < 4; g++) lb[pid * 4 + g] = lsum[g];
    }
    __syncthreads();
    if (kh == 0) {
#pragma unroll
        for (int g = 0; g < 2; g++)
#pragma unroll
            for (int di = 0; di < 4; di++)
#pragma unroll
                for (int j = 0; j < 4; j++)
                    oacc[g][di][j] += cb[(((g << 2) | di) * 4 + j) * 128 + pid];
#pragma unroll
        for (int g = 0; g < 4; g++) lsum[g] += lb[pid * 4 + g];
    }
    __syncthreads();
    if (kh == 1) {
#pragma unroll
        for (int g = 2; g < 4; g++)
#pragma unroll
            for (int di = 0; di < 4; di++)
#pragma unroll
                for (int j = 0; j < 4; j++)
                    cb[((((g - 2) << 2) | di) * 4 + j) * 128 + pid] = oacc[g][di][j];
    }
    __syncthreads();
    if (kh == 0) {
#pragma unroll
        for (int g = 2; g < 4; g++)
#pragma unroll
            for (int di = 0; di < 4; di++)
#pragma unroll
                for (int j = 0; j < 4; j++)
                    oacc[g][di][j] += cb[((((g - 2) << 2) | di) * 4 + j) * 128 + pid];

        for (int g = 0; g < 4; g++) {
            float inv = 1.f / lsum[g];
            const int qrow = q0 + pw * 64 + g * 16 + l15;
            for (int di = 0; di < 4; di++) {
                half4 hv;
                hv[0] = (_Float16)(oacc[g][di][0] * inv);
                hv[1] = (_Float16)(oacc[g][di][1] * inv);
                hv[2] = (_Float16)(oacc[g][di][2] * inv);
                hv[3] = (_Float16)(oacc[g][di][3] * inv);
                *(half4*)(&AO[(size_t)(b * 2048 + qrow) * 1024 + h * 64 + di * 16 + quad * 4]) = hv;
            }
        }
    }
}

// ---------------- proj GEMM: out[4096,1024] = AO @ Wp + bp (fp32 out) ----------------

__global__ __launch_bounds__(256) void gemm_proj(const _Float16* __restrict__ A,
                                                 const _Float16* __restrict__ Bt,
                                                 const float* __restrict__ bias,
                                                 float* __restrict__ out) {
    __shared__ _Float16 As[64][64];    //  8 KB
    __shared__ _Float16 Bs[128][64];   // 16 KB
    const int tid = threadIdx.x;
    const int lin = blockIdx.x + 8 * blockIdx.y;
    const int xcd = lin & 7, slot = lin >> 3;     // slot 0..63
    const int n0 = (slot >> 3) * 128;
    const int m0 = (xcd * 8 + (slot & 7)) * 64;
    const int wave = tid >> 6, lane = tid & 63;
    const int quad = lane >> 4, l15 = lane & 15;
    const int sw = l15 & 7;
    const int ldrowA = wave * 16 + (lane >> 3);
    const int ldrowB = wave * 32 + (lane >> 3);
    const int ldslot = (lane & 7) * 8;
    const int gcolA = (((lane & 7) ^ (ldrowA & 7))) * 8;
    const int gcolB = (((lane & 7) ^ (ldrowB & 7))) * 8;

    f32x4 acc[4][2] = {};
    for (int k0 = 0; k0 < 1024; k0 += 64) {
        __syncthreads();
        for (int i = 0; i < 2; i++) {
            int r = ldrowA + i * 8;
            GLOBAL_LOAD_LDS16(&A[(size_t)(m0 + r) * 1024 + k0 + gcolA], &As[r][ldslot]);
        }
        for (int i = 0; i < 4; i++) {
            int r = ldrowB + i * 8;
            GLOBAL_LOAD_LDS16(&Bt[(size_t)(n0 + r) * 1024 + k0 + gcolB], &Bs[r][ldslot]);
        }
        __syncthreads();
        for (int kk = 0; kk < 64; kk += 32) {
            const int rcol = (((kk >> 3) + quad) ^ sw) * 8;
            half8 af[4], bf[2];
            for (int mi = 0; mi < 4; mi++)
                af[mi] = *(const half8*)(&As[mi * 16 + l15][rcol]);
            for (int ni = 0; ni < 2; ni++)
                bf[ni] = *(const half8*)(&Bs[wave * 32 + ni * 16 + l15][rcol]);
            for (int mi = 0; mi < 4; mi++)
                for (int ni = 0; ni < 2; ni++)
                    acc[mi][ni] = MFMA16(af[mi], bf[ni], acc[mi][ni]);
        }
    }
    for (int mi = 0; mi < 4; mi++)
        for (int ni = 0; ni < 2; ni++) {
            int gn = n0 + wave * 32 + ni * 16 + l15;
            float bv = bias[gn];
            for (int r = 0; r < 4; r++) {
                int gm = m0 + mi * 16 + quad * 4 + r;
                out[(size_t)gm * 1024 + gn] = acc[mi][ni][r] + bv;
            }
        }
}

// ---------------- launch ----------------

extern "C" void kernel_launch(void* const* d_in, const int* in_sizes, int n_in,
                              void* d_out, int out_size, void* d_ws, size_t ws_size,
                              hipStream_t stream) {
    const float* x     = (const float*)d_in[0];
    const float* Wqkv  = (const float*)d_in[1];
    const float* bqkv  = (const float*)d_in[2];
    const float* Wproj = (const float*)d_in[3];
    const float* bproj = (const float*)d_in[4];
    float* out = (float*)d_out;

    char* ws = (char*)d_ws;
    const size_t MB = 1024 * 1024;
    _Float16* Xh  = (_Float16*)(ws + 0 * MB);   // [4096][1024]   8 MB
    _Float16* Wqt = (_Float16*)(ws + 8 * MB);   // [3072][1024]   6 MB
    _Float16* Wpt = (_Float16*)(ws + 14 * MB);  // [1024][1024]   2 MB
    _Float16* Qg  = (_Float16*)(ws + 16 * MB);  // [32][2048][64] 8 MB (pre-scaled)
    _Float16* Kg  = (_Float16*)(ws + 24 * MB);  // [32][2048][64] 8 MB
    _Float16* Vtg = (_Float16*)(ws + 32 * MB);  // [32][64][2048] 8 MB (sigma cols)
    _Float16* AO  = (_Float16*)(ws + 40 * MB);  // [4096][1024]   8 MB

    prep_kernel<<<8192, 256, 0, stream>>>(x, Wqkv, Wproj, Xh, Wqt, Wpt);
    gemm_qkv<<<192, 512, 0, stream>>>(Xh, Wqt, bqkv, Qg, Kg, Vtg);
    attn_kernel<<<dim3(32, 16), 256, 0, stream>>>(Qg, Kg, Vtg, AO);
    gemm_proj<<<dim3(8, 64), 256, 0, stream>>>(AO, Wpt, bproj, out);
}

// Round 9
// 173.654 us; speedup vs baseline: 1.1620x; 1.0007x over previous
//
#include <hip/hip_runtime.h>

typedef _Float16 half8 __attribute__((ext_vector_type(8)));
typedef _Float16 half4 __attribute__((ext_vector_type(4)));
typedef _Float16 half2 __attribute__((ext_vector_type(2)));
typedef float f32x4 __attribute__((ext_vector_type(4)));
typedef unsigned int u32x4 __attribute__((ext_vector_type(4)));

#define MFMA16(a, b, c) __builtin_amdgcn_mfma_f32_16x16x32_f16((a), (b), (c), 0, 0, 0)
#define EXP2F(x) __builtin_amdgcn_exp2f(x)

#define GLOBAL_LOAD_LDS16(gptr, lptr)                                        \
    __builtin_amdgcn_global_load_lds(                                        \
        (const __attribute__((address_space(1))) void*)(gptr),               \
        (__attribute__((address_space(3))) void*)(lptr), 16, 0, 0)

// Q is pre-scaled by softmax_scale * log2(e) in the qkv epilogue.
#define QSCALE 0.18033688f  // 0.125 * log2(e)

// R9: BARRIER without sched_barrier(0). m141 measured sched_barrier(0)
// order-pinning as a 912->510 TF regression on exactly this template; the
// memory clobber + s_barrier is sufficient for ordering (all LDS/GLL deps are
// compiler-tracked C++ memory ops; MFMA ordering follows register dataflow).
#define BARRIER() do { asm volatile("" ::: "memory");                      \
                       __builtin_amdgcn_s_barrier();                        \
                       asm volatile("" ::: "memory"); } while (0)
#define WAITV(N) asm volatile("s_waitcnt vmcnt(" #N ")" ::: "memory")

// ---------------- fused prep: cast x + transpose-cast both weights ----------------

__global__ __launch_bounds__(256) void prep_kernel(const float* __restrict__ x,
                                                   const float* __restrict__ Wqkv,
                                                   const float* __restrict__ Wproj,
                                                   _Float16* __restrict__ Xh,
                                                   _Float16* __restrict__ Wqt,
                                                   _Float16* __restrict__ Wpt) {
    const int bid = blockIdx.x;
    const int tid = threadIdx.x;
    if (bid < 4096) {
        int i = bid * 1024 + tid * 4;
        float4 v = *(const float4*)(x + i);
        half4 h = {(_Float16)v.x, (_Float16)v.y, (_Float16)v.z, (_Float16)v.w};
        *(half4*)(Xh + i) = h;
        return;
    }
    __shared__ _Float16 tile[32][33];
    const float* W;
    _Float16* Wt;
    int n0, k0, N;
    if (bid < 7168) {
        int t = bid - 4096;
        W = Wqkv; Wt = Wqt; N = 3072;
        n0 = (t % 96) * 32; k0 = (t / 96) * 32;
    } else {
        int t = bid - 7168;
        W = Wproj; Wt = Wpt; N = 1024;
        n0 = (t & 31) * 32; k0 = (t >> 5) * 32;
    }
    int c = tid & 31, r4 = tid >> 5;
    for (int i = 0; i < 4; i++) {
        int r = r4 + i * 8;
        tile[r][c] = (_Float16)W[(k0 + r) * N + n0 + c];
    }
    __syncthreads();
    for (int i = 0; i < 4; i++) {
        int r = r4 + i * 8;  // n within tile
        Wt[(n0 + r) * 1024 + k0 + c] = tile[c][r];
    }
}

// ---------------- QKV GEMM: 256x256-tile 8-phase counted-vmcnt (T2+T3+T4+T5) ----------------

#define LOFF(ROW, Q) ((((ROW) >> 1) * 64) + \
    ((((((ROW) & 1) << 2) | (Q)) ^ (((ROW) >> 1) & 7)) * 8))

__global__ __launch_bounds__(512) void gemm_qkv(const _Float16* __restrict__ A,
                                                const _Float16* __restrict__ Bt,
                                                const float* __restrict__ bias,
                                                _Float16* __restrict__ Qo,
                                                _Float16* __restrict__ Ko,
                                                _Float16* __restrict__ Vto) {
    __shared__ _Float16 L[65536];  // [buf2][op2][kk2][8192 halfs] = 128 KB
    const int tid = threadIdx.x;
    const int lin = blockIdx.x;
    const int xcd = lin & 7, slot = lin >> 3;      // slot 0..23
    const int m0 = (xcd * 2 + slot / 12) * 256;    // 16 m-tiles
    const int n0 = (slot % 12) * 256;              // 12 n-tiles
    const int wave = tid >> 6, lane = tid & 63;
    const int wm = wave >> 2, wn = wave & 3;       // 2M x 4N waves
    const int quad = lane >> 4, l15 = lane & 15;

    // staging: linear GLL dest (lane*16B), pre-swizzled global source
    const int s8 = (tid & 7) ^ ((tid >> 3) & 7);   // logical 16B-slot (0..7)
    const int srow = (tid >> 3) * 2 + (s8 >> 2);   // logical row (round 0)
    const int scol = (s8 & 3) * 8;                 // logical col within kk-half
    const _Float16* Asrc = A + (size_t)(m0 + srow) * 1024 + scol;
    const _Float16* Bsrc = Bt + (size_t)(n0 + srow) * 1024 + scol;
    _Float16* Ldst = L + tid * 8;

#define STG(OP, KK, KT) do {                                                  \
    const _Float16* _g = ((OP) ? Bsrc : Asrc) + ((KT) & 15) * 64 + (KK) * 32; \
    _Float16* _l = Ldst + ((KT) & 1) * 32768 + (OP) * 16384 + (KK) * 8192;    \
    GLOBAL_LOAD_LDS16(_g, _l);                                                \
    GLOBAL_LOAD_LDS16(_g + 128 * 1024, _l + 4096);                            \
} while (0)

    const int arow = wm * 128 + l15;   // + MH*64 + fi*16
    const int brow = wn * 64 + l15;    // + nf*16

    f32x4 acc[8][4] = {};
    half8 af[4], bf[4];

#define PHASE(BUF, KK, MH, RDB, SOP, SKK, SKT, W4) do {                        \
    const _Float16* _ab = L + (BUF) * 32768 + (KK) * 8192;                     \
    const _Float16* _bb = _ab + 16384;                                         \
    if (RDB) {                                                                 \
        _Pragma("unroll") for (int nf = 0; nf < 4; nf++)                       \
            bf[nf] = *(const half8*)(_bb + LOFF(brow + nf * 16, quad));        \
    }                                                                          \
    _Pragma("unroll") for (int fi = 0; fi < 4; fi++)                           \
        af[fi] = *(const half8*)(_ab + LOFF(arow + (MH) * 64 + fi * 16, quad));\
    STG(SOP, SKK, SKT);                                                        \
    BARRIER();                                                                 \
    __builtin_amdgcn_s_setprio(1);                                             \
    _Pragma("unroll") for (int fi = 0; fi < 4; fi++)                           \
        _Pragma("unroll") for (int nf = 0; nf < 4; nf++)                       \
            acc[(MH) * 4 + fi][nf] = MFMA16(af[fi], bf[nf],                    \
                                            acc[(MH) * 4 + fi][nf]);           \
    __builtin_amdgcn_s_setprio(0);                                             \
    if (W4) { WAITV(4); }                                                      \
    BARRIER();                                                                 \
} while (0)

    // prologue: tile0 complete + tile1 lo-halves in flight
    STG(0, 0, 0); STG(1, 0, 0); STG(0, 1, 0); STG(1, 1, 0);
    STG(0, 0, 1); STG(1, 0, 1);
    WAITV(4);           // tile0's 8 loads done; tile1 lo (4 loads) in flight
    BARRIER();

    for (int i = 0; i < 8; ++i) {
        const int ta = 2 * i, tb = 2 * i + 1;
        PHASE(0, 0, 0, 1, 0, 1, tb,     0);  // p1: +stage A-hi(t+1)
        PHASE(0, 0, 1, 0, 1, 1, tb,     0);  // p2: +stage B-hi(t+1)
        PHASE(0, 1, 0, 1, 0, 0, ta + 2, 0);  // p3: +stage A-lo(t+2)
        PHASE(0, 1, 1, 0, 1, 0, ta + 2, 1);  // p4: +stage B-lo(t+2); vmcnt(4)
        PHASE(1, 0, 0, 1, 0, 1, ta + 2, 0);  // p5: +stage A-hi(t+2)
        PHASE(1, 0, 1, 0, 1, 1, ta + 2, 0);  // p6: +stage B-hi(t+2)
        PHASE(1, 1, 0, 1, 0, 0, tb + 2, 0);  // p7: +stage A-lo(t+3)
        PHASE(1, 1, 1, 0, 1, 0, tb + 2, 1);  // p8: +stage B-lo(t+3); vmcnt(4)
    }
    WAITV(0);  // drain trailing (wrapped) stages before epilogue / endpgm

    // epilogue: scatter to Q (scaled) / K / Vt. which is block-uniform.
    // V columns are stored SIGMA-PERMUTED within each 32-t block:
    //   t = 16h + 4q + r  ->  p = (t & ~31) | (q<<3) | (h<<2) | r
    // so attn's PV B-operand (native P pack) and V agree on k with a plain
    // contiguous LDS copy (no swizzled LDS stores -> no bank conflicts).
    const int which = n0 >> 10;
    const int hh = ((n0 + wn * 64) & 1023) >> 6;  // head idx (wave-uniform)
    float bv[4];
    const int gnb = n0 + wn * 64;
#pragma unroll
    for (int nf = 0; nf < 4; nf++) bv[nf] = bias[gnb + nf * 16 + l15];

#pragma unroll
    for (int mf = 0; mf < 8; mf++) {
        const int gm0 = m0 + wm * 128 + mf * 16 + quad * 4;
        const int b = gm0 >> 11, t0 = gm0 & 2047;
        const int bh = b * 16 + hh;
#pragma unroll
        for (int nf = 0; nf < 4; nf++) {
            const int dh = nf * 16 + l15;
            if (which == 2) {
                half4 hv;
#pragma unroll
                for (int r = 0; r < 4; r++)
                    hv[r] = (_Float16)(acc[mf][nf][r] + bv[nf]);
                const int p0 = (t0 & ~31) | (((t0 >> 2) & 3) << 3) | (((t0 >> 4) & 1) << 2);
                *(half4*)(&Vto[(size_t)(bh * 64 + dh) * 2048 + p0]) = hv;
            } else if (which == 0) {
#pragma unroll
                for (int r = 0; r < 4; r++)
                    Qo[((size_t)bh * 2048 + t0 + r) * 64 + dh] =
                        (_Float16)((acc[mf][nf][r] + bv[nf]) * QSCALE);
            } else {
#pragma unroll
                for (int r = 0; r < 4; r++)
                    Ko[((size_t)bh * 2048 + t0 + r) * 64 + dh] =
                        (_Float16)(acc[mf][nf][r] + bv[nf]);
            }
        }
    }
#undef PHASE
#undef STG
}

// ---------------- flash attention R9: R8 structure, de-pinned barriers ----------------
// Identical to R8 (g=4, KVBLK=64, 3-ring counted vmcnt, all-GLL, 0 conflicts);
// only the BARRIER macro lost its sched_barrier(0) fences (m141 lesson).

static __device__ inline unsigned pk2(float a, float b) {
    half2 p;
    p.x = (_Float16)a;
    p.y = (_Float16)b;
    return __builtin_bit_cast(unsigned, p);
}

__global__ __launch_bounds__(256, 2) void attn_kernel(const _Float16* __restrict__ Qg,
                                                      const _Float16* __restrict__ Kg,
                                                      const _Float16* __restrict__ Vtg,
                                                      _Float16* __restrict__ AO) {
    __shared__ __align__(16) _Float16 Lsh[3][8192];  // [ring][K 4096 | V 4096] = 48 KB

    const int tid = threadIdx.x;
    const int bh = blockIdx.x;
    const int q0 = blockIdx.y * 128;
    const int b = bh >> 4, h = bh & 15;
    const int wave = tid >> 6, lane = tid & 63;
    const int pw = wave & 1;     // q half: rows [pw*64, +64)
    const int kh = wave >> 1;    // k half of the 64-tile: [kh*32, +32)
    const int quad = lane >> 4, l15 = lane & 15;
    const int akey = l15 & 7;

    half8 qf[4][2];
#pragma unroll
    for (int g = 0; g < 4; g++) {
        const int qrow = q0 + pw * 64 + g * 16 + l15;
#pragma unroll
        for (int kk = 0; kk < 2; kk++)
            qf[g][kk] = *(const half8*)(&Qg[(bh * 2048 + qrow) * 64 + kk * 32 + quad * 8]);
    }

    const _Float16* Kbase = Kg + (size_t)bh * 2048 * 64;
    const _Float16* Vbase = Vtg + (size_t)bh * 64 * 2048;

    // GLL staging: linear dest (tid*16B), pre-swizzled global source.
    const int srow = tid >> 3, sc8 = tid & 7;
    const int scol = (sc8 ^ (srow & 7)) * 8;       // (srow+32)&7 == srow&7
    const _Float16* Ksrc = Kbase + (size_t)srow * 64 + scol;
    const _Float16* Vsrc = Vbase + (size_t)srow * 2048 + scol;

#define STAGE(BUF, KT) do {                                                    \
    const size_t _ko = (size_t)(KT) * 4096;                                    \
    const int _vo = (KT) * 64;                                                 \
    _Float16* _lb = &Lsh[BUF][0];                                              \
    GLOBAL_LOAD_LDS16(Ksrc + _ko,              _lb + tid * 8);                 \
    GLOBAL_LOAD_LDS16(Ksrc + _ko + 2048,       _lb + 2048 + tid * 8);          \
    GLOBAL_LOAD_LDS16(Vsrc + _vo,              _lb + 4096 + tid * 8);          \
    GLOBAL_LOAD_LDS16(Vsrc + _vo + 32 * 2048,  _lb + 6144 + tid * 8);          \
} while (0)

    f32x4 oacc[4][4] = {};
    float lsum[4] = {0.f, 0.f, 0.f, 0.f};

    // prologue: tiles 0,1 staged (tile1 stays in flight past the barrier)
    STAGE(0, 0);
    STAGE(1, 1);
    WAITV(4);        // tile0's 4 loads (and qf) done; tile1's 4 in flight
    BARRIER();

    int cur = 0;
    for (int kt = 0; kt < 32; kt++) {
        int nxt = cur + 2; if (nxt >= 3) nxt -= 3;
        STAGE(nxt, (kt + 2) & 31);          // wrapped at kt=30/31 (ledger-uniform)

        const _Float16* Kb = &Lsh[cur][0];
        const _Float16* Vb = &Lsh[cur][4096];
        const int r0 = kh * 32 + l15;        // k-16-block j=0
        const int r1 = kh * 32 + 16 + l15;   // k-16-block j=1
        half8 kaa = *(const half8*)(Kb + r0 * 64 + (quad ^ akey) * 8);
        half8 kab = *(const half8*)(Kb + r0 * 64 + ((quad + 4) ^ akey) * 8);
        half8 kba = *(const half8*)(Kb + r1 * 64 + (quad ^ akey) * 8);
        half8 kbb = *(const half8*)(Kb + r1 * 64 + ((quad + 4) ^ akey) * 8);
        half8 av[4];
#pragma unroll
        for (int di = 0; di < 4; di++)
            av[di] = *(const half8*)(Vb + (di * 16 + l15) * 64 +
                                     ((kh * 4 + quad) ^ akey) * 8);

        __builtin_amdgcn_s_setprio(1);
#pragma unroll
        for (int g = 0; g < 4; g++) {
            f32x4 sA = {}, sB = {};
            sA = MFMA16(kaa, qf[g][0], sA);
            sA = MFMA16(kab, qf[g][1], sA);
            sB = MFMA16(kba, qf[g][0], sB);
            sB = MFMA16(kbb, qf[g][1], sB);
            float a0 = EXP2F(sA[0]), a1 = EXP2F(sA[1]);
            float a2 = EXP2F(sA[2]), a3 = EXP2F(sA[3]);
            float b0 = EXP2F(sB[0]), b1 = EXP2F(sB[1]);
            float b2 = EXP2F(sB[2]), b3 = EXP2F(sB[3]);
            lsum[g] += ((a0 + a1) + (a2 + a3)) + ((b0 + b1) + (b2 + b3));
            u32x4 w = {pk2(a0, a1), pk2(a2, a3), pk2(b0, b1), pk2(b2, b3)};
            half8 bP = __builtin_bit_cast(half8, w);
#pragma unroll
            for (int di = 0; di < 4; di++)
                oacc[g][di] = MFMA16(av[di], bP, oacc[g][di]);
        }
        __builtin_amdgcn_s_setprio(0);

        WAITV(4);      // tile kt+1 landed; tile kt+2's 4 loads stay in flight
        BARRIER();
        cur = cur + 1; if (cur >= 3) cur -= 3;
    }
#undef STAGE

    // quad-reduce lsum (each lane held its quad's 8-k partial)
#pragma unroll
    for (int g = 0; g < 4; g++) {
        lsum[g] += __shfl_xor(lsum[g], 16, 64);
        lsum[g] += __shfl_xor(lsum[g], 32, 64);
    }

    WAITV(0);   // drain wrapped stages before LDS reuse
    // ---- cross-wave (kh) combine: partials are pure sums. Two passes. ----
    float* cb = (float*)&Lsh[0][0];      // 4096 floats (16 KB = ring buf 0)
    float* lb = cb + 4096;               // 512 floats (start of ring buf 1)
    const int pid = pw * 64 + lane;      // 0..127, lane-major -> conflict-free

    __syncthreads();
    if (kh == 1) {
#pragma unroll
        for (int g = 0; g < 2; g++)
#pragma unroll
            for (int di = 0; di < 4; di++)
#pragma unroll
                for (int j = 0; j < 4; j++)
                    cb[(((g << 2) | di) * 4 + j) * 128 + pid] = oacc[g][di][j];
#pragma unroll
        for (int g = 0; g < 4; g++) lb[pid * 4 + g] = lsum[g];
    }
    __syncthreads();
    if (kh == 0) {
#pragma unroll
        for (int g = 0; g < 2; g++)
#pragma unroll
            for (int di = 0; di < 4; di++)
#pragma unroll
                for (int j = 0; j < 4; j++)
                    oacc[g][di][j] += cb[(((g << 2) | di) * 4 + j) * 128 + pid];
#pragma unroll
        for (int g = 0; g < 4; g++) lsum[g] += lb[pid * 4 + g];
    }
    __syncthreads();
    if (kh == 1) {
#pragma unroll
        for (int g = 2; g < 4; g++)
#pragma unroll
            for (int di = 0; di < 4; di++)
#pragma unroll
                for (int j = 0; j < 4; j++)
                    cb[((((g - 2) << 2) | di) * 4 + j) * 128 + pid] = oacc[g][di][j];
    }
    __syncthreads();
    if (kh == 0) {
#pragma unroll
        for (int g = 2; g < 4; g++)
#pragma unroll
            for (int di = 0; di < 4; di++)
#pragma unroll
                for (int j = 0; j < 4; j++)
                    oacc[g][di][j] += cb[((((g - 2) << 2) | di) * 4 + j) * 128 + pid];

        for (int g = 0; g < 4; g++) {
            float inv = 1.f / lsum[g];
            const int qrow = q0 + pw * 64 + g * 16 + l15;
            for (int di = 0; di < 4; di++) {
                half4 hv;
                hv[0] = (_Float16)(oacc[g][di][0] * inv);
                hv[1] = (_Float16)(oacc[g][di][1] * inv);
                hv[2] = (_Float16)(oacc[g][di][2] * inv);
                hv[3] = (_Float16)(oacc[g][di][3] * inv);
                *(half4*)(&AO[(size_t)(b * 2048 + qrow) * 1024 + h * 64 + di * 16 + quad * 4]) = hv;
            }
        }
    }
}

// ---------------- proj GEMM: out[4096,1024] = AO @ Wp + bp (fp32 out) ----------------

__global__ __launch_bounds__(256) void gemm_proj(const _Float16* __restrict__ A,
                                                 const _Float16* __restrict__ Bt,
                                                 const float* __restrict__ bias,
                                                 float* __restrict__ out) {
    __shared__ _Float16 As[64][64];    //  8 KB
    __shared__ _Float16 Bs[128][64];   // 16 KB
    const int tid = threadIdx.x;
    const int lin = blockIdx.x + 8 * blockIdx.y;
    const int xcd = lin & 7, slot = lin >> 3;     // slot 0..63
    const int n0 = (slot >> 3) * 128;
    const int m0 = (xcd * 8 + (slot & 7)) * 64;
    const int wave = tid >> 6, lane = tid & 63;
    const int quad = lane >> 4, l15 = lane & 15;
    const int sw = l15 & 7;
    const int ldrowA = wave * 16 + (lane >> 3);
    const int ldrowB = wave * 32 + (lane >> 3);
    const int ldslot = (lane & 7) * 8;
    const int gcolA = (((lane & 7) ^ (ldrowA & 7))) * 8;
    const int gcolB = (((lane & 7) ^ (ldrowB & 7))) * 8;

    f32x4 acc[4][2] = {};
    for (int k0 = 0; k0 < 1024; k0 += 64) {
        __syncthreads();
        for (int i = 0; i < 2; i++) {
            int r = ldrowA + i * 8;
            GLOBAL_LOAD_LDS16(&A[(size_t)(m0 + r) * 1024 + k0 + gcolA], &As[r][ldslot]);
        }
        for (int i = 0; i < 4; i++) {
            int r = ldrowB + i * 8;
            GLOBAL_LOAD_LDS16(&Bt[(size_t)(n0 + r) * 1024 + k0 + gcolB], &Bs[r][ldslot]);
        }
        __syncthreads();
        for (int kk = 0; kk < 64; kk += 32) {
            const int rcol = (((kk >> 3) + quad) ^ sw) * 8;
            half8 af[4], bf[2];
            for (int mi = 0; mi < 4; mi++)
                af[mi] = *(const half8*)(&As[mi * 16 + l15][rcol]);
            for (int ni = 0; ni < 2; ni++)
                bf[ni] = *(const half8*)(&Bs[wave * 32 + ni * 16 + l15][rcol]);
            for (int mi = 0; mi < 4; mi++)
                for (int ni = 0; ni < 2; ni++)
                    acc[mi][ni] = MFMA16(af[mi], bf[ni], acc[mi][ni]);
        }
    }
    for (int mi = 0; mi < 4; mi++)
        for (int ni = 0; ni < 2; ni++) {
            int gn = n0 + wave * 32 + ni * 16 + l15;
            float bv = bias[gn];
            for (int r = 0; r < 4; r++) {
                int gm = m0 + mi * 16 + quad * 4 + r;
                out[(size_t)gm * 1024 + gn] = acc[mi][ni][r] + bv;
            }
        }
}

// ---------------- launch ----------------

extern "C" void kernel_launch(void* const* d_in, const int* in_sizes, int n_in,
                              void* d_out, int out_size, void* d_ws, size_t ws_size,
                              hipStream_t stream) {
    const float* x     = (const float*)d_in[0];
    const float* Wqkv  = (const float*)d_in[1];
    const float* bqkv  = (const float*)d_in[2];
    const float* Wproj = (const float*)d_in[3];
    const float* bproj = (const float*)d_in[4];
    float* out = (float*)d_out;

    char* ws = (char*)d_ws;
    const size_t MB = 1024 * 1024;
    _Float16* Xh  = (_Float16*)(ws + 0 * MB);   // [4096][1024]   8 MB
    _Float16* Wqt = (_Float16*)(ws + 8 * MB);   // [3072][1024]   6 MB
    _Float16* Wpt = (_Float16*)(ws + 14 * MB);  // [1024][1024]   2 MB
    _Float16* Qg  = (_Float16*)(ws + 16 * MB);  // [32][2048][64] 8 MB (pre-scaled)
    _Float16* Kg  = (_Float16*)(ws + 24 * MB);  // [32][2048][64] 8 MB
    _Float16* Vtg = (_Float16*)(ws + 32 * MB);  // [32][64][2048] 8 MB (sigma cols)
    _Float16* AO  = (_Float16*)(ws + 40 * MB);  // [4096][1024]   8 MB

    prep_kernel<<<8192, 256, 0, stream>>>(x, Wqkv, Wproj, Xh, Wqt, Wpt);
    gemm_qkv<<<192, 512, 0, stream>>>(Xh, Wqt, bqkv, Qg, Kg, Vtg);
    attn_kernel<<<dim3(32, 16), 256, 0, stream>>>(Qg, Kg, Vtg, AO);
    gemm_proj<<<dim3(8, 64), 256, 0, stream>>>(AO, Wpt, bproj, out);
}